// Round 4
// baseline (2778.817 us; speedup 1.0000x reference)
//
#include <hip/hip_runtime.h>
#include <cstdint>
#include <cstddef>

// FullQKAttention (b=4, s=4096, d=64 fp32).
// R4: 2 blocks/CU (64KB LDS single-buffered K+V^T, 512 thr, lb(512,4)),
// 512 blocks = one 32-row i-tile each, heavy-first for LPT balance.
// Swapped-operand MFMA QK^T (mfma(K,Q) -> D[j,i]) + PV MFMA with shfl-gathered
// A (zero-padded K), bf16 hi/lo x3 everywhere. exp2 with log2e folded into
// rscale. setprio around MFMA clusters. Sweep2 recomputes QK^T, writes
// normalized attn; upper triangle zero-filled in-kernel.

#define S_LEN 4096
#define D_DIM 64
#define N_B   4

typedef __bf16 bf16x8 __attribute__((ext_vector_type(8)));
typedef float  f32x4  __attribute__((ext_vector_type(4)));

static __device__ __forceinline__ unsigned pk2(float a, float b) {
  union { __bf16 h[2]; unsigned u; } t;
  t.h[0] = (__bf16)a; t.h[1] = (__bf16)b;
  return t.u;
}
static __device__ __forceinline__ float rlo(float x) { return x - (float)(__bf16)x; }

// K LDS [j][k] bf16, 16B-granule XOR swizzle (conflict-floor b128 reads)
static __device__ __forceinline__ int kidx(int j, int k) {
  return j * 64 + (k ^ ((j & 7) << 3));
}
// V^T LDS [e][j] bf16, granule-8 XOR swizzle on j by (e&15)
static __device__ __forceinline__ int vtidx(int e, int j) {
  return e * 128 + (((j >> 3) ^ (e & 15)) << 3) + (j & 7);
}

// ---------------- kernel A: per-row normalization scale ----------------
__global__ __launch_bounds__(256) void knorm_kernel(const float* __restrict__ qk,
                                                    float* __restrict__ rscale) {
  const int row  = blockIdx.x * 4 + (threadIdx.x >> 6);
  const int lane = threadIdx.x & 63;
  float x = qk[(size_t)row * D_DIM + lane];
  float ss = x * x;
  #pragma unroll
  for (int m = 1; m < 64; m <<= 1) ss += __shfl_xor(ss, m, 64);
  if (lane == 0) {
    float n = fmaxf(sqrtf(ss), 1e-12f);
    rscale[row] = 0.18033688011112042f / n;   // d^-1/2 * log2(e) / ||k||
  }
}

static __device__ __forceinline__ void loadK(const float* __restrict__ qb, int j0,
                                             int sj, int skq, float4 kr[4]) {
  #pragma unroll
  for (int it = 0; it < 4; ++it)
    kr[it] = *(const float4*)&qb[(size_t)(j0 + it*32 + sj) * D_DIM + skq*4];
}
static __device__ __forceinline__ void writeK(unsigned short* Khi, unsigned short* Klo,
                                              int sj, int skq, const float4 kr[4]) {
  #pragma unroll
  for (int it = 0; it < 4; ++it) {
    int ki = kidx(it*32 + sj, skq*4);
    uint2 H = make_uint2(pk2(kr[it].x, kr[it].y), pk2(kr[it].z, kr[it].w));
    uint2 L = make_uint2(pk2(rlo(kr[it].x), rlo(kr[it].y)),
                         pk2(rlo(kr[it].z), rlo(kr[it].w)));
    *(uint2*)&Khi[ki] = H;
    *(uint2*)&Klo[ki] = L;
  }
}
static __device__ __forceinline__ void loadV(const float* __restrict__ vb0, int j0,
                                             int w, int ve, float vr[4][4]) {
  #pragma unroll
  for (int git = 0; git < 4; ++git) {
    int j4 = git*32 + w*4;
    #pragma unroll
    for (int r = 0; r < 4; ++r)
      vr[git][r] = vb0[(size_t)(j0 + j4 + r) * D_DIM + ve];
  }
}
static __device__ __forceinline__ void writeV(unsigned short* VThi, unsigned short* VTlo,
                                              int w, int ve, const float vr[4][4]) {
  #pragma unroll
  for (int git = 0; git < 4; ++git) {
    int j4 = git*32 + w*4;
    int vi = vtidx(ve, j4);
    uint2 H = make_uint2(pk2(vr[git][0], vr[git][1]), pk2(vr[git][2], vr[git][3]));
    uint2 L = make_uint2(pk2(rlo(vr[git][0]), rlo(vr[git][1])),
                         pk2(rlo(vr[git][2]), rlo(vr[git][3])));
    *(uint2*)&VThi[vi] = H;
    *(uint2*)&VTlo[vi] = L;
  }
}

// ---------------- fused attention kernel ----------------
__global__ __launch_bounds__(512, 4) void attn_fused(
    const float* __restrict__ qk, const float* __restrict__ v,
    float* __restrict__ out, float* __restrict__ attn,
    const float* __restrict__ rscale) {

  __shared__ __align__(16) unsigned char smem[65536];
  __shared__ float RsumS[8][32];
  __shared__ float RinvS[32];
  unsigned short* Khi  = (unsigned short*)smem;       // 16 KB
  unsigned short* Klo  = Khi + 8192;                  // 16 KB
  unsigned short* VThi = Khi + 16384;                 // 16 KB
  unsigned short* VTlo = Khi + 24576;                 // 16 KB
  float* Red = (float*)smem;                          // epilogue alias (64 KB)

  const int tid = threadIdx.x;
  const int w   = tid >> 6;
  const int l   = tid & 63;
  const int lr  = l & 15;
  const int lq  = l >> 4;
  const int skq = tid & 15;   // K-stage: dim quad
  const int sj  = tid >> 4;   // K-stage: j base
  const int ve  = tid & 63;   // V-stage: e column

  const int b    = blockIdx.x & 3;          // batch pinned per XCD pair
  const int slot = blockIdx.x >> 2;         // 0..127
  const int t0   = 127 - slot;              // heavy tiles dispatched first
  const int i0   = t0 << 5;
  const int n1   = (t0 >> 2) + 1;           // causal j-tile count

  const float* qb  = qk + (size_t)b * S_LEN * D_DIM;
  const float* vb0 = v  + (size_t)b * S_LEN * D_DIM;
  const float* rsb = rscale + (size_t)b * S_LEN;
  float* attb = attn + (size_t)b * S_LEN * S_LEN;

  // PV shfl-gather lane constants (A-frag k=lq*8..+8, real only for lq<2)
  const int s0   = (((lq << 1)    ) & 3) * 16 + lr;
  const int s1   = (((lq << 1) | 1) & 3) * 16 + lr;
  const bool vld = (lq < 2);

  // ---- Q fragments hi/lo (B-operand: col i = lr, k-chunk lq*8) ----
  bf16x8 Qh[2][2], Ql[2][2];
  #pragma unroll
  for (int f = 0; f < 2; ++f)
    #pragma unroll
    for (int ks = 0; ks < 2; ++ks) {
      const float* ap = qb + (size_t)(i0 + f*16 + lr) * D_DIM + ks*32 + lq*8;
      float4 x0 = *(const float4*)ap;
      float4 x1 = *(const float4*)(ap + 4);
      union { unsigned u[4]; bf16x8 v; } H, L;
      H.u[0] = pk2(x0.x, x0.y); H.u[1] = pk2(x0.z, x0.w);
      H.u[2] = pk2(x1.x, x1.y); H.u[3] = pk2(x1.z, x1.w);
      L.u[0] = pk2(rlo(x0.x), rlo(x0.y)); L.u[1] = pk2(rlo(x0.z), rlo(x0.w));
      L.u[2] = pk2(rlo(x1.x), rlo(x1.y)); L.u[3] = pk2(rlo(x1.z), rlo(x1.w));
      Qh[f][ks] = H.v; Ql[f][ks] = L.v;
    }

  f32x4 pvacc[2][4];
  #pragma unroll
  for (int f = 0; f < 2; ++f)
    #pragma unroll
    for (int ef = 0; ef < 4; ++ef) pvacc[f][ef] = (f32x4){0.f, 0.f, 0.f, 0.f};
  float rs_acc[2] = {0.f, 0.f};

  float4 kr[4]; float vr[4][4]; float4 rs_cur, rs_next;

  // =================== sweep 1: rowsum + PV ===================
  loadK(qb, 0, sj, skq, kr);
  loadV(vb0, 0, w, ve, vr);
  rs_cur = *(const float4*)&rsb[w*16 + lq*4];
  writeK(Khi, Klo, sj, skq, kr);
  writeV(VThi, VTlo, w, ve, vr);
  __syncthreads();

  for (int jt = 0; jt < n1; ++jt) {
    const int j0 = jt << 7;
    const bool more = (jt + 1 < n1);
    if (more) {                         // T14: issue next-tile loads early
      loadK(qb, j0 + 128, sj, skq, kr);
      loadV(vb0, j0 + 128, w, ve, vr);
      rs_next = *(const float4*)&rsb[j0 + 128 + w*16 + lq*4];
    }

    // ---- QK^T (swapped): D[j,i]; lane: i=lr, j=w*16+lq*4+r ----
    f32x4 aq[2];
    aq[0] = (f32x4){0.f,0.f,0.f,0.f}; aq[1] = (f32x4){0.f,0.f,0.f,0.f};
    __builtin_amdgcn_s_setprio(1);
    #pragma unroll
    for (int ks = 0; ks < 2; ++ks) {
      const int ki = kidx(w*16 + lr, ks*32 + lq*8);
      bf16x8 Ah = *(const bf16x8*)&Khi[ki];
      bf16x8 Al = *(const bf16x8*)&Klo[ki];
      #pragma unroll
      for (int f = 0; f < 2; ++f) {
        aq[f] = __builtin_amdgcn_mfma_f32_16x16x32_bf16(Ah, Qh[f][ks], aq[f], 0, 0, 0);
        aq[f] = __builtin_amdgcn_mfma_f32_16x16x32_bf16(Ah, Ql[f][ks], aq[f], 0, 0, 0);
        aq[f] = __builtin_amdgcn_mfma_f32_16x16x32_bf16(Al, Qh[f][ks], aq[f], 0, 0, 0);
      }
    }
    __builtin_amdgcn_s_setprio(0);

    // ---- exp2 / mask / pack (logits bounded: no max pass; diag exact) ----
    const float rsa[4] = {rs_cur.x, rs_cur.y, rs_cur.z, rs_cur.w};
    unsigned pwh0[2], pwh1[2], pwl0[2], pwl1[2];
    #pragma unroll
    for (int f = 0; f < 2; ++f) {
      const int ig = i0 + f*16 + lr;
      float p[4];
      #pragma unroll
      for (int r = 0; r < 4; ++r) {
        const int jg = j0 + w*16 + lq*4 + r;
        float pp = exp2f(aq[f][r] * rsa[r]);
        if (jg > ig) pp = 0.f;
        else if (jg == ig) pp = (ig == 0) ? 1.f : 0.f;
        p[r] = pp;
      }
      rs_acc[f] += (p[0] + p[1]) + (p[2] + p[3]);
      pwh0[f] = pk2(p[0], p[1]);           pwh1[f] = pk2(p[2], p[3]);
      pwl0[f] = pk2(rlo(p[0]), rlo(p[1])); pwl1[f] = pk2(rlo(p[2]), rlo(p[3]));
    }

    // ---- gather PV A-frags (P[i=lr][k-chunk lq*8]) ----
    union U { unsigned u[4]; bf16x8 v; } AH[2], AL[2];
    #pragma unroll
    for (int f = 0; f < 2; ++f) {
      unsigned h0 = __shfl(pwh0[f], s0, 64), h1 = __shfl(pwh1[f], s0, 64);
      unsigned h2 = __shfl(pwh0[f], s1, 64), h3 = __shfl(pwh1[f], s1, 64);
      unsigned g0 = __shfl(pwl0[f], s0, 64), g1 = __shfl(pwl1[f], s0, 64);
      unsigned g2 = __shfl(pwl0[f], s1, 64), g3 = __shfl(pwl1[f], s1, 64);
      AH[f].u[0] = vld ? h0 : 0u; AH[f].u[1] = vld ? h1 : 0u;
      AH[f].u[2] = vld ? h2 : 0u; AH[f].u[3] = vld ? h3 : 0u;
      AL[f].u[0] = vld ? g0 : 0u; AL[f].u[1] = vld ? g1 : 0u;
      AL[f].u[2] = vld ? g2 : 0u; AL[f].u[3] = vld ? g3 : 0u;
    }

    // ---- PV MFMAs ----
    __builtin_amdgcn_s_setprio(1);
    #pragma unroll
    for (int ef = 0; ef < 4; ++ef) {
      const int vi = vtidx(ef*16 + lr, w*16 + (lq & 1)*8);
      bf16x8 Bh = *(const bf16x8*)&VThi[vi];
      bf16x8 Bl = *(const bf16x8*)&VTlo[vi];
      #pragma unroll
      for (int f = 0; f < 2; ++f) {
        pvacc[f][ef] = __builtin_amdgcn_mfma_f32_16x16x32_bf16(AH[f].v, Bh, pvacc[f][ef], 0, 0, 0);
        pvacc[f][ef] = __builtin_amdgcn_mfma_f32_16x16x32_bf16(AH[f].v, Bl, pvacc[f][ef], 0, 0, 0);
        pvacc[f][ef] = __builtin_amdgcn_mfma_f32_16x16x32_bf16(AL[f].v, Bh, pvacc[f][ef], 0, 0, 0);
      }
    }
    __builtin_amdgcn_s_setprio(0);

    if (more) {
      __syncthreads();                  // all LDS reads of tile jt done
      writeK(Khi, Klo, sj, skq, kr);
      writeV(VThi, VTlo, w, ve, vr);
      rs_cur = rs_next;
      __syncthreads();                  // tile jt+1 staged
    }
  }
  __syncthreads();                      // last-tile LDS reads done (Red alias)

  // =================== finalize: rowsum -> rinv, out ===================
  #pragma unroll
  for (int f = 0; f < 2; ++f) {
    float x = rs_acc[f];
    x += __shfl_xor(x, 16, 64);
    x += __shfl_xor(x, 32, 64);
    rs_acc[f] = x;
  }
  if (l < 16) { RsumS[w][l] = rs_acc[0]; RsumS[w][16 + l] = rs_acc[1]; }
  // Red writes, bank-swizzled by +lq*4 (reader reconstructs lq from iloc)
  #pragma unroll
  for (int f = 0; f < 2; ++f)
    #pragma unroll
    for (int ef = 0; ef < 4; ++ef)
      #pragma unroll
      for (int r = 0; r < 4; ++r)
        Red[w*2048 + (f*16 + lq*4 + r)*64 + ((ef*16 + lr + lq*4) & 63)] = pvacc[f][ef][r];
  __syncthreads();
  if (tid < 32) {
    float s = 0.f;
    #pragma unroll
    for (int ww = 0; ww < 8; ++ww) s += RsumS[ww][tid];
    RinvS[tid] = 1.0f / s;
  }
  __syncthreads();
  {
    const int iloc = tid >> 4, e4 = (tid & 15) << 2;
    const int lq2  = (iloc >> 2) & 3;
    const int c    = (e4 + lq2*4) & 63;
    f32x4 s = (f32x4){0.f, 0.f, 0.f, 0.f};
    #pragma unroll
    for (int ww = 0; ww < 8; ++ww)
      s += *(const f32x4*)&Red[ww*2048 + iloc*64 + c];
    const float ri = RinvS[iloc];
    float4 o = make_float4(s[0]*ri, s[1]*ri, s[2]*ri, s[3]*ri);
    *(float4*)&out[((size_t)b * S_LEN + i0 + iloc) * D_DIM + e4] = o;
  }
  const float rinv_reg[2] = { RinvS[lr], RinvS[16 + lr] };
  __syncthreads();                      // Red/RinvS reads done before restage

  // =================== sweep 2: write normalized attn ===================
  loadK(qb, 0, sj, skq, kr);
  rs_cur = *(const float4*)&rsb[w*16 + lq*4];
  writeK(Khi, Klo, sj, skq, kr);
  __syncthreads();

  for (int jt = 0; jt < n1; ++jt) {
    const int j0 = jt << 7;
    const bool more = (jt + 1 < n1);
    if (more) {
      loadK(qb, j0 + 128, sj, skq, kr);
      rs_next = *(const float4*)&rsb[j0 + 128 + w*16 + lq*4];
    }

    f32x4 aq[2];
    aq[0] = (f32x4){0.f,0.f,0.f,0.f}; aq[1] = (f32x4){0.f,0.f,0.f,0.f};
    __builtin_amdgcn_s_setprio(1);
    #pragma unroll
    for (int ks = 0; ks < 2; ++ks) {
      const int ki = kidx(w*16 + lr, ks*32 + lq*8);
      bf16x8 Ah = *(const bf16x8*)&Khi[ki];
      bf16x8 Al = *(const bf16x8*)&Klo[ki];
      #pragma unroll
      for (int f = 0; f < 2; ++f) {
        aq[f] = __builtin_amdgcn_mfma_f32_16x16x32_bf16(Ah, Qh[f][ks], aq[f], 0, 0, 0);
        aq[f] = __builtin_amdgcn_mfma_f32_16x16x32_bf16(Ah, Ql[f][ks], aq[f], 0, 0, 0);
        aq[f] = __builtin_amdgcn_mfma_f32_16x16x32_bf16(Al, Qh[f][ks], aq[f], 0, 0, 0);
      }
    }
    __builtin_amdgcn_s_setprio(0);

    const float rsa[4] = {rs_cur.x, rs_cur.y, rs_cur.z, rs_cur.w};
    #pragma unroll
    for (int f = 0; f < 2; ++f) {
      const int ig = i0 + f*16 + lr;
      float4 st; float* stp = (float*)&st;
      #pragma unroll
      for (int r = 0; r < 4; ++r) {
        const int jg = j0 + w*16 + lq*4 + r;
        float pp = exp2f(aq[f][r] * rsa[r]);
        if (jg > ig) pp = 0.f;
        else if (jg == ig) pp = (ig == 0) ? 1.f : 0.f;
        stp[r] = pp * rinv_reg[f];
      }
      *(float4*)&attb[(size_t)ig * S_LEN + j0 + w*16 + lq*4] = st;
    }

    if (more) {
      __syncthreads();
      writeK(Khi, Klo, sj, skq, kr);
      rs_cur = rs_next;
      __syncthreads();
    }
  }

  // zero-fill columns beyond the causal tile range
  {
    const int c0 = n1 << 5;   // first untouched float4 column
    const float4 z = make_float4(0.f, 0.f, 0.f, 0.f);
    #pragma unroll
    for (int rr = 0; rr < 4; ++rr) {
      float4* dst = (float4*)(attb + (size_t)(i0 + w*4 + rr) * S_LEN);
      for (int c = c0 + l; c < 1024; c += 64) dst[c] = z;
    }
  }
}

extern "C" void kernel_launch(void* const* d_in, const int* in_sizes, int n_in,
                              void* d_out, int out_size, void* d_ws, size_t ws_size,
                              hipStream_t stream) {
  const float* qk = (const float*)d_in[0];
  const float* v  = (const float*)d_in[1];
  float* out  = (float*)d_out;
  float* attn = (float*)d_out + (size_t)N_B * S_LEN * D_DIM;
  float* rscale = (float*)d_ws;   // 16384 floats

  knorm_kernel<<<dim3(N_B * S_LEN / 4), dim3(256), 0, stream>>>(qk, rscale);
  attn_fused<<<dim3(512), dim3(512), 0, stream>>>(qk, v, out, attn, rscale);
}